// Round 4
// baseline (2075.166 us; speedup 1.0000x reference)
//
#include <hip/hip_runtime.h>

#define L_PAD 8192
#define HS    25
#define ES    50
#define G4    100   // 4*H
#define LOG2E 1.44269504088896340736f

// -------- workspace layout --------
// zs2   : float2[2][L_PAD*50]   packed gate preacts: zs2[d][t*50+j] = (z[j], z[j+50])
// wstar : float2[2][50]         h* @ Wh, same packing
// cstar : float [2][25]         frozen cell state

__device__ __forceinline__ float rl_f(float v, int lane) {
    return __int_as_float(__builtin_amdgcn_readlane(__float_as_int(v), lane));
}
__device__ __forceinline__ float fast_sigmoid(float x) {
    return __builtin_amdgcn_rcpf(1.f + __builtin_amdgcn_exp2f(x * (-LOG2E)));
}
__device__ __forceinline__ float fast_tanh(float x) {
    // 2*sigmoid(2x) - 1
    return fmaf(__builtin_amdgcn_rcpf(1.f + __builtin_amdgcn_exp2f(x * (-2.f * LOG2E))), 2.f, -1.f);
}

// ---------------- kernel 1: pre-activations (parallel) ----------------
__global__ __launch_bounds__(64) void k_pre(
    const int* __restrict__ tok, const int* __restrict__ plen,
    const float* __restrict__ Ef, const float* __restrict__ Wif, const float* __restrict__ bf,
    const float* __restrict__ Eb, const float* __restrict__ Wib, const float* __restrict__ bb,
    float2* __restrict__ zs2)
{
    const int b = blockIdx.x;
    const int d = b & 1;
    const int t = b >> 1;
    const int j = threadIdx.x;
    const int len = *plen;

    int src;
    if (d == 0) src = t;
    else        src = (t < len) ? (len - 1 - t) : (L_PAD - 1 - (t - len));
    const int token = tok[src];

    const float* __restrict__ E  = d ? Eb  : Ef;
    const float* __restrict__ Wi = d ? Wib : Wif;
    const float* __restrict__ bs = d ? bb  : bf;

    __shared__ float e[ES];
    if (j < ES) e[j] = E[(size_t)token * ES + j];
    __syncthreads();
    if (j >= 50) return;

    float ax = bs[j], ay = bs[j + 50];
    float bx = 0.f,  by = 0.f;
    #pragma unroll
    for (int k = 0; k < ES; k += 2) {
        float e0 = e[k], e1 = e[k + 1];
        ax = fmaf(e0, Wi[k * G4 + j],            ax);
        ay = fmaf(e0, Wi[k * G4 + j + 50],       ay);
        bx = fmaf(e1, Wi[(k + 1) * G4 + j],      bx);
        by = fmaf(e1, Wi[(k + 1) * G4 + j + 50], by);
    }
    zs2[(size_t)d * (L_PAD * 50) + t * 50 + j] = make_float2(ax + bx, ay + by);
}

// ---------------- kernel 2: the serial recurrence (latency-bound) ----------------
// one wave per direction. lane j in [0,50): gates (j, j+50).
//   lanes 0..24  -> (i_k, g_k),  lanes 25..49 -> (f_k, o_k)
// NO ARRAYS in this kernel: round-1/3 showed VGPR_Count=36 — the float2 W[25]
// alloca survived SROA and lived in scratch, re-loaded every serial step.
// 50 named scalars + asm pins force W into VGPRs for the whole loop.
#define PIN(x) asm volatile("" : "+v"(x))
#define LW(k)  float wx##k = Wh[(k)*G4 + jj]; float wy##k = Wh[(k)*G4 + jj + 50]; \
               PIN(wx##k); PIN(wy##k);
#define FM(k, a) { float hk = rl_f(h, k); \
                   ax##a = fmaf(hk, wx##k, ax##a); ay##a = fmaf(hk, wy##k, ay##a); }
#define EP(k)  { float hk = rl_f(h, k); \
                 ex = fmaf(hk, wx##k, ex); ey = fmaf(hk, wy##k, ey); }

__global__ __launch_bounds__(64, 1) void k_seq(
    const float* __restrict__ Whf, const float* __restrict__ Whb,
    const int* __restrict__ plen,
    const float2* __restrict__ zs2_all,
    float* __restrict__ out,
    float2* __restrict__ wstar, float* __restrict__ cstar)
{
    const int d = blockIdx.x;
    const int j = threadIdx.x;
    const int len = *plen;
    const float* __restrict__ Wh = d ? Whb : Whf;
    const float2* __restrict__ z = zs2_all + (size_t)d * (L_PAD * 50);
    const int jj = (j < 50) ? j : 0;

    // 50 loop-invariant weights, individually named + pinned to VGPRs
    LW(0)  LW(1)  LW(2)  LW(3)  LW(4)  LW(5)  LW(6)  LW(7)  LW(8)  LW(9)
    LW(10) LW(11) LW(12) LW(13) LW(14) LW(15) LW(16) LW(17) LW(18) LW(19)
    LW(20) LW(21) LW(22) LW(23) LW(24)

    // branch-free activation constants: second gate is tanh for lanes<25, sigmoid otherwise
    const bool  isG = (j < 25);
    const float my = isG ? (-2.f * LOG2E) : (-LOG2E);
    const float ca = isG ? 2.f : 1.f;
    const float cb = isG ? -1.f : 0.f;

    float c = 0.f, h = 0.f;   // lanes 0..24 carry real state; other lanes' values never read
    const float2* __restrict__ zb = z + jj;
    // prefetch pipeline, distance 4 (zs2 mostly in remote-XCD L2 / L3: ~400-600 cyc)
    float2 z0 = zb[0], z1 = zb[50], z2 = zb[100], z3 = zb[150];
    float* outp = out + d * HS + j;   // stride 50 floats per step

    for (int t = 0; t < len; ++t) {
        int tp = t + 4; tp = (tp < L_PAD) ? tp : (L_PAD - 1);
        float2 zf = zb[tp * 50];

        // z + h @ Wh  — 4 independent accumulator chains, all-scalar SSA
        float ax0 = z0.x, ay0 = z0.y;
        float ax1 = 0.f,  ay1 = 0.f;
        float ax2 = 0.f,  ay2 = 0.f;
        float ax3 = 0.f,  ay3 = 0.f;
        FM(0,0)  FM(1,1)  FM(2,2)  FM(3,3)
        FM(4,0)  FM(5,1)  FM(6,2)  FM(7,3)
        FM(8,0)  FM(9,1)  FM(10,2) FM(11,3)
        FM(12,0) FM(13,1) FM(14,2) FM(15,3)
        FM(16,0) FM(17,1) FM(18,2) FM(19,3)
        FM(20,0) FM(21,1) FM(22,2) FM(23,3)
        FM(24,0)
        float px = (ax0 + ax1) + (ax2 + ax3);
        float py = (ay0 + ay1) + (ay2 + ay3);

        float sa = fast_sigmoid(px);                     // i (lanes<25) / f (lanes>=25)
        float ry = __builtin_amdgcn_rcpf(1.f + __builtin_amdgcn_exp2f(py * my));
        float sb = fmaf(ry, ca, cb);                     // g=tanh (lanes<25) / o=sigmoid

        float f_ = __shfl(sa, j + 25);                   // lane k reads lane k+25
        float o_ = __shfl(sb, j + 25);
        float nc = fmaf(f_, c, sa * sb);                 // f*c + i*g
        float nh = o_ * fast_tanh(nc);
        c = nc;                                          // unconditional: upper-lane
        h = nh;                                          //  garbage is never readlane'd
        if (j < 25) outp[t * 50] = nh;                   // out[t*50 + d*25 + j]
        z0 = z1; z1 = z2; z2 = z3; z3 = zf;
    }

    // epilogue: w* = h* @ Wh (packed) and c* for the frozen tail
    float ex = 0.f, ey = 0.f;
    EP(0)  EP(1)  EP(2)  EP(3)  EP(4)  EP(5)  EP(6)  EP(7)  EP(8)  EP(9)
    EP(10) EP(11) EP(12) EP(13) EP(14) EP(15) EP(16) EP(17) EP(18) EP(19)
    EP(20) EP(21) EP(22) EP(23) EP(24)
    if (j < 50) wstar[d * 50 + j] = make_float2(ex, ey);
    if (j < 25) cstar[d * HS + j] = c;
}

// ---------------- kernel 3: frozen-carry tail (parallel) ----------------
__global__ __launch_bounds__(256) void k_tail(
    const int* __restrict__ plen,
    const float2* __restrict__ zs2_all,
    const float2* __restrict__ wstar, const float* __restrict__ cstar,
    float* __restrict__ out)
{
    const int tid = blockIdx.x * 256 + threadIdx.x;
    if (tid >= L_PAD * 50) return;
    const int col = tid % 50;
    const int t   = tid / 50;
    const int len = *plen;
    if (t < len) return;
    const int d = col / HS;
    const int j = col % HS;

    const float2* __restrict__ z = zs2_all + (size_t)d * (L_PAD * 50);
    float2 zi = z[t * 50 + j];
    float2 zq = z[t * 50 + j + 25];
    float2 wi = wstar[d * 50 + j];
    float2 wq = wstar[d * 50 + j + 25];

    float i_ = fast_sigmoid(zi.x + wi.x);
    float g_ = fast_tanh  (zi.y + wi.y);
    float f_ = fast_sigmoid(zq.x + wq.x);
    float o_ = fast_sigmoid(zq.y + wq.y);

    float nc = fmaf(f_, cstar[d * HS + j], i_ * g_);
    out[t * 50 + col] = o_ * fast_tanh(nc);
}

extern "C" void kernel_launch(void* const* d_in, const int* in_sizes, int n_in,
                              void* d_out, int out_size, void* d_ws, size_t ws_size,
                              hipStream_t stream)
{
    const int*   tok  = (const int*)  d_in[0];
    const int*   plen = (const int*)  d_in[1];
    const float* Ef   = (const float*)d_in[2];
    const float* Wif  = (const float*)d_in[3];
    const float* Whf  = (const float*)d_in[4];
    const float* bf   = (const float*)d_in[5];
    const float* Eb   = (const float*)d_in[6];
    const float* Wib  = (const float*)d_in[7];
    const float* Whb  = (const float*)d_in[8];
    const float* bb   = (const float*)d_in[9];
    float* out = (float*)d_out;

    float2* zs2   = (float2*)d_ws;
    float2* wstar = (float2*)((char*)d_ws + (size_t)2 * L_PAD * 50 * sizeof(float2));
    float*  cstar = (float*)((char*)wstar + 100 * sizeof(float2));

    k_pre <<<2 * L_PAD, 64, 0, stream>>>(tok, plen, Ef, Wif, bf, Eb, Wib, bb, zs2);
    k_seq <<<2, 64, 0, stream>>>(Whf, Whb, plen, zs2, out, wstar, cstar);
    k_tail<<<(L_PAD * 50 + 255) / 256, 256, 0, stream>>>(plen, zs2, wstar, cstar, out);
}

// Round 5
// 2071.857 us; speedup vs baseline: 1.0016x; 1.0016x over previous
//
#include <hip/hip_runtime.h>

#define L_PAD 8192
#define HS    25
#define ES    50
#define G4    100   // 4*H
#define LOG2E 1.44269504088896340736f

// -------- workspace layout --------
// zs2   : float2[2][L_PAD*50]   packed gate preacts: zs2[d][t*50+j] = (z[j], z[j+50])
// wstar : float2[2][50]         h* @ Wh, same packing
// cstar : float [2][25]         frozen cell state

__device__ __forceinline__ float rl_f(float v, int lane) {
    return __int_as_float(__builtin_amdgcn_readlane(__float_as_int(v), lane));
}
__device__ __forceinline__ float fast_sigmoid(float x) {
    return __builtin_amdgcn_rcpf(1.f + __builtin_amdgcn_exp2f(x * (-LOG2E)));
}
__device__ __forceinline__ float fast_tanh(float x) {
    // 2*sigmoid(2x) - 1
    return fmaf(__builtin_amdgcn_rcpf(1.f + __builtin_amdgcn_exp2f(x * (-2.f * LOG2E))), 2.f, -1.f);
}

// ---------------- kernel 1: pre-activations (parallel) ----------------
__global__ __launch_bounds__(64) void k_pre(
    const int* __restrict__ tok, const int* __restrict__ plen,
    const float* __restrict__ Ef, const float* __restrict__ Wif, const float* __restrict__ bf,
    const float* __restrict__ Eb, const float* __restrict__ Wib, const float* __restrict__ bb,
    float2* __restrict__ zs2)
{
    const int b = blockIdx.x;
    const int d = b & 1;
    const int t = b >> 1;
    const int j = threadIdx.x;
    const int len = *plen;

    int src;
    if (d == 0) src = t;
    else        src = (t < len) ? (len - 1 - t) : (L_PAD - 1 - (t - len));
    const int token = tok[src];

    const float* __restrict__ E  = d ? Eb  : Ef;
    const float* __restrict__ Wi = d ? Wib : Wif;
    const float* __restrict__ bs = d ? bb  : bf;

    __shared__ float e[ES];
    if (j < ES) e[j] = E[(size_t)token * ES + j];
    __syncthreads();
    if (j >= 50) return;

    float ax = bs[j], ay = bs[j + 50];
    float bx = 0.f,  by = 0.f;
    #pragma unroll
    for (int k = 0; k < ES; k += 2) {
        float e0 = e[k], e1 = e[k + 1];
        ax = fmaf(e0, Wi[k * G4 + j],            ax);
        ay = fmaf(e0, Wi[k * G4 + j + 50],       ay);
        bx = fmaf(e1, Wi[(k + 1) * G4 + j],      bx);
        by = fmaf(e1, Wi[(k + 1) * G4 + j + 50], by);
    }
    zs2[(size_t)d * (L_PAD * 50) + t * 50 + j] = make_float2(ax + bx, ay + by);
}

// ---------------- kernel 2: the serial recurrence (latency-bound) ----------------
// one wave per direction. lane j in [0,50): gates (j, j+50).
//   lanes 0..24  -> (i_k, g_k),  lanes 25..49 -> (f_k, o_k)
// Round-4 evidence: __launch_bounds__(64,1) + asm pins still gave VGPR_Count=40
// (an 8-waves/EU budget) and unchanged time -> the RA spilled all 50 pinned
// weights to scratch and reloads them every serial step. amdgpu_waves_per_eu(1,1)
// pins the occupancy target itself: budget = full 512-VGPR file.
#define PIN(x) asm volatile("" : "+v"(x))
#define LW(k)  float wx##k = Wh[(k)*G4 + jj]; float wy##k = Wh[(k)*G4 + jj + 50]; \
               PIN(wx##k); PIN(wy##k);
#define FM(k, a) { float hk = rl_f(h, k); \
                   ax##a = fmaf(hk, wx##k, ax##a); ay##a = fmaf(hk, wy##k, ay##a); }
#define EP(k)  { float hk = rl_f(h, k); \
                 ex = fmaf(hk, wx##k, ex); ey = fmaf(hk, wy##k, ey); }

__global__ __launch_bounds__(64, 1)
__attribute__((amdgpu_waves_per_eu(1, 1)))
void k_seq(
    const float* __restrict__ Whf, const float* __restrict__ Whb,
    const int* __restrict__ plen,
    const float2* __restrict__ zs2_all,
    float* __restrict__ out,
    float2* __restrict__ wstar, float* __restrict__ cstar)
{
    const int d = blockIdx.x;
    const int j = threadIdx.x;
    const int len = *plen;
    const float* __restrict__ Wh = d ? Whb : Whf;
    const float2* __restrict__ z = zs2_all + (size_t)d * (L_PAD * 50);
    const int jj = (j < 50) ? j : 0;

    // 50 loop-invariant weights, individually named + pinned to VGPRs
    LW(0)  LW(1)  LW(2)  LW(3)  LW(4)  LW(5)  LW(6)  LW(7)  LW(8)  LW(9)
    LW(10) LW(11) LW(12) LW(13) LW(14) LW(15) LW(16) LW(17) LW(18) LW(19)
    LW(20) LW(21) LW(22) LW(23) LW(24)

    // branch-free activation constants: second gate is tanh for lanes<25, sigmoid otherwise
    const bool  isG = (j < 25);
    const float my = isG ? (-2.f * LOG2E) : (-LOG2E);
    const float ca = isG ? 2.f : 1.f;
    const float cb = isG ? -1.f : 0.f;

    float c = 0.f, h = 0.f;   // lanes 0..24 carry real state; other lanes' values never read
    const float2* __restrict__ zb = z + jj;
    // prefetch pipeline, distance 4 (zs2 mostly in remote-XCD L2 / L3: ~400-600 cyc)
    float2 z0 = zb[0], z1 = zb[50], z2 = zb[100], z3 = zb[150];
    float* outp = out + d * HS + j;   // stride 50 floats per step

    for (int t = 0; t < len; ++t) {
        int tp = t + 4; tp = (tp < L_PAD) ? tp : (L_PAD - 1);
        float2 zf = zb[tp * 50];

        // z + h @ Wh  — 4 independent accumulator chains, all-scalar SSA
        float ax0 = z0.x, ay0 = z0.y;
        float ax1 = 0.f,  ay1 = 0.f;
        float ax2 = 0.f,  ay2 = 0.f;
        float ax3 = 0.f,  ay3 = 0.f;
        FM(0,0)  FM(1,1)  FM(2,2)  FM(3,3)
        FM(4,0)  FM(5,1)  FM(6,2)  FM(7,3)
        FM(8,0)  FM(9,1)  FM(10,2) FM(11,3)
        FM(12,0) FM(13,1) FM(14,2) FM(15,3)
        FM(16,0) FM(17,1) FM(18,2) FM(19,3)
        FM(20,0) FM(21,1) FM(22,2) FM(23,3)
        FM(24,0)
        float px = (ax0 + ax1) + (ax2 + ax3);
        float py = (ay0 + ay1) + (ay2 + ay3);

        float sa = fast_sigmoid(px);                     // i (lanes<25) / f (lanes>=25)
        float ry = __builtin_amdgcn_rcpf(1.f + __builtin_amdgcn_exp2f(py * my));
        float sb = fmaf(ry, ca, cb);                     // g=tanh (lanes<25) / o=sigmoid

        float f_ = __shfl(sa, j + 25);                   // lane k reads lane k+25
        float o_ = __shfl(sb, j + 25);
        float nc = fmaf(f_, c, sa * sb);                 // f*c + i*g
        float nh = o_ * fast_tanh(nc);
        c = nc;                                          // unconditional: upper-lane
        h = nh;                                          //  garbage is never readlane'd
        if (j < 25) outp[t * 50] = nh;                   // out[t*50 + d*25 + j]
        z0 = z1; z1 = z2; z2 = z3; z3 = zf;
    }

    // epilogue: w* = h* @ Wh (packed) and c* for the frozen tail
    float ex = 0.f, ey = 0.f;
    EP(0)  EP(1)  EP(2)  EP(3)  EP(4)  EP(5)  EP(6)  EP(7)  EP(8)  EP(9)
    EP(10) EP(11) EP(12) EP(13) EP(14) EP(15) EP(16) EP(17) EP(18) EP(19)
    EP(20) EP(21) EP(22) EP(23) EP(24)
    if (j < 50) wstar[d * 50 + j] = make_float2(ex, ey);
    if (j < 25) cstar[d * HS + j] = c;
}

// ---------------- kernel 3: frozen-carry tail (parallel) ----------------
__global__ __launch_bounds__(256) void k_tail(
    const int* __restrict__ plen,
    const float2* __restrict__ zs2_all,
    const float2* __restrict__ wstar, const float* __restrict__ cstar,
    float* __restrict__ out)
{
    const int tid = blockIdx.x * 256 + threadIdx.x;
    if (tid >= L_PAD * 50) return;
    const int col = tid % 50;
    const int t   = tid / 50;
    const int len = *plen;
    if (t < len) return;
    const int d = col / HS;
    const int j = col % HS;

    const float2* __restrict__ z = zs2_all + (size_t)d * (L_PAD * 50);
    float2 zi = z[t * 50 + j];
    float2 zq = z[t * 50 + j + 25];
    float2 wi = wstar[d * 50 + j];
    float2 wq = wstar[d * 50 + j + 25];

    float i_ = fast_sigmoid(zi.x + wi.x);
    float g_ = fast_tanh  (zi.y + wi.y);
    float f_ = fast_sigmoid(zq.x + wq.x);
    float o_ = fast_sigmoid(zq.y + wq.y);

    float nc = fmaf(f_, cstar[d * HS + j], i_ * g_);
    out[t * 50 + col] = o_ * fast_tanh(nc);
}

extern "C" void kernel_launch(void* const* d_in, const int* in_sizes, int n_in,
                              void* d_out, int out_size, void* d_ws, size_t ws_size,
                              hipStream_t stream)
{
    const int*   tok  = (const int*)  d_in[0];
    const int*   plen = (const int*)  d_in[1];
    const float* Ef   = (const float*)d_in[2];
    const float* Wif  = (const float*)d_in[3];
    const float* Whf  = (const float*)d_in[4];
    const float* bf   = (const float*)d_in[5];
    const float* Eb   = (const float*)d_in[6];
    const float* Wib  = (const float*)d_in[7];
    const float* Whb  = (const float*)d_in[8];
    const float* bb   = (const float*)d_in[9];
    float* out = (float*)d_out;

    float2* zs2   = (float2*)d_ws;
    float2* wstar = (float2*)((char*)d_ws + (size_t)2 * L_PAD * 50 * sizeof(float2));
    float*  cstar = (float*)((char*)wstar + 100 * sizeof(float2));

    k_pre <<<2 * L_PAD, 64, 0, stream>>>(tok, plen, Ef, Wif, bf, Eb, Wib, bb, zs2);
    k_seq <<<2, 64, 0, stream>>>(Whf, Whb, plen, zs2, out, wstar, cstar);
    k_tail<<<(L_PAD * 50 + 255) / 256, 256, 0, stream>>>(plen, zs2, wstar, cstar, out);
}